// Round 1
// baseline (722.822 us; speedup 1.0000x reference)
//
#include <hip/hip_runtime.h>
#include <math.h>

#define C 128
#define EPSV 1e-16f

__device__ __forceinline__ float waveAllReduceAdd(float v) {
    #pragma unroll
    for (int off = 32; off >= 1; off >>= 1) v += __shfl_xor(v, off);
    return v;
}

// ---------------- sort-by-dst (CSR build) ----------------

__global__ __launch_bounds__(256) void zero_kernel(int* __restrict__ p, int n) {
    int i = blockIdx.x * 256 + threadIdx.x;
    if (i < n) p[i] = 0;
}

__global__ __launch_bounds__(256) void hist_kernel(const int* __restrict__ col, int* __restrict__ counts, int e) {
    int i = blockIdx.x * 256 + threadIdx.x;
    if (i < e) atomicAdd(&counts[col[i]], 1);
}

__global__ __launch_bounds__(256) void scanA_kernel(const int* __restrict__ counts, int* __restrict__ row_ptr,
                                                    int* __restrict__ bsums, int n) {
    __shared__ int sh[256];
    int tid = threadIdx.x;
    int i = blockIdx.x * 256 + tid;
    int v = (i < n) ? counts[i] : 0;
    sh[tid] = v;
    __syncthreads();
    #pragma unroll
    for (int off = 1; off < 256; off <<= 1) {
        int t = (tid >= off) ? sh[tid - off] : 0;
        __syncthreads();
        sh[tid] += t;
        __syncthreads();
    }
    if (i < n) row_ptr[i] = sh[tid] - v;            // chunk-local exclusive
    if (tid == 255) bsums[blockIdx.x] = sh[255];    // chunk total
}

__global__ __launch_bounds__(256) void scanB_kernel(int* __restrict__ bsums, int nb) {
    __shared__ int sh[256];
    int tid = threadIdx.x;
    int v = (tid < nb) ? bsums[tid] : 0;
    sh[tid] = v;
    __syncthreads();
    #pragma unroll
    for (int off = 1; off < 256; off <<= 1) {
        int t = (tid >= off) ? sh[tid - off] : 0;
        __syncthreads();
        sh[tid] += t;
        __syncthreads();
    }
    bsums[tid] = sh[tid] - v;                       // exclusive over block sums
}

__global__ __launch_bounds__(256) void scanC_kernel(int* __restrict__ row_ptr, const int* __restrict__ bsums,
                                                    int* __restrict__ cursor, int n) {
    int i = blockIdx.x * 256 + threadIdx.x;
    if (i < n) {
        int rp = row_ptr[i] + bsums[blockIdx.x];
        row_ptr[i] = rp;
        cursor[i] = rp;
    }
}

__global__ __launch_bounds__(256) void scatter_kernel(const int* __restrict__ rowA, const int* __restrict__ colA,
                                                      int* __restrict__ cursor, int* __restrict__ csr, int e) {
    int i = blockIdx.x * 256 + threadIdx.x;
    if (i < e) {
        int c = colA[i];
        int p = atomicAdd(&cursor[c], 1);
        csr[p] = rowA[i];
    }
}

// ---------------- GEMM: O[n][128] = A[n][128] @ W[128][128] ----------------
// thread = 4 rows x 4 cols

__global__ __launch_bounds__(256) void gemm_kernel(const float* __restrict__ A, const float* __restrict__ W,
                                                   float* __restrict__ O, int nRowGroups) {
    int t = blockIdx.x * 256 + threadIdx.x;
    int rg = t >> 5;
    if (rg >= nRowGroups) return;
    int cg = t & 31;
    const float4* W4 = (const float4*)W;
    const float* a0 = A + (size_t)rg * 4 * C;
    float4 acc0 = {0,0,0,0}, acc1 = {0,0,0,0}, acc2 = {0,0,0,0}, acc3 = {0,0,0,0};
    #pragma unroll 8
    for (int k = 0; k < C; k++) {
        float4 w = W4[k * 32 + cg];
        float av0 = a0[k];
        float av1 = a0[C + k];
        float av2 = a0[2 * C + k];
        float av3 = a0[3 * C + k];
        acc0.x += av0 * w.x; acc0.y += av0 * w.y; acc0.z += av0 * w.z; acc0.w += av0 * w.w;
        acc1.x += av1 * w.x; acc1.y += av1 * w.y; acc1.z += av1 * w.z; acc1.w += av1 * w.w;
        acc2.x += av2 * w.x; acc2.y += av2 * w.y; acc2.z += av2 * w.z; acc2.w += av2 * w.w;
        acc3.x += av3 * w.x; acc3.y += av3 * w.y; acc3.z += av3 * w.z; acc3.w += av3 * w.w;
    }
    float4* O4 = (float4*)(O + (size_t)rg * 4 * C);
    O4[cg] = acc0;
    O4[32 + cg] = acc1;
    O4[64 + cg] = acc2;
    O4[96 + cg] = acc3;
}

// ---------------- per-node attention dot precompute ----------------
// al[n] = h[n].att_l ; ar[n] = h[n].att_r    (wave per node)

__global__ __launch_bounds__(256) void att_kernel(const float* __restrict__ H, const float* __restrict__ attl,
                                                  const float* __restrict__ attr, float* __restrict__ al,
                                                  float* __restrict__ ar, int n) {
    int node = blockIdx.x * 4 + (threadIdx.x >> 6);
    int lane = threadIdx.x & 63;
    if (node >= n) return;
    float2 h2 = *(const float2*)&H[(size_t)node * C + 2 * lane];
    float2 l2 = *(const float2*)&attl[2 * lane];
    float2 r2 = *(const float2*)&attr[2 * lane];
    float sl = h2.x * l2.x + h2.y * l2.y;
    float sr = h2.x * r2.x + h2.y * r2.y;
    sl = waveAllReduceAdd(sl);
    sr = waveAllReduceAdd(sr);
    if (lane == 0) { al[node] = sl; ar[node] = sr; }
}

// ---------------- per-node aggregation (online softmax, wave per node) -----

__global__ __launch_bounds__(256) void agg_kernel(const float* __restrict__ H, const int* __restrict__ csr,
                                                  const int* __restrict__ row_ptr, const int* __restrict__ counts,
                                                  const float* __restrict__ al, const float* __restrict__ ar,
                                                  const float* __restrict__ bvec, float* __restrict__ O,
                                                  int n, int doRelu) {
    int node = blockIdx.x * 4 + (threadIdx.x >> 6);
    int lane = threadIdx.x & 63;
    if (node >= n) return;

    float2 hi = *(const float2*)&H[(size_t)node * C + 2 * lane];
    float aln = al[node];
    float arn = ar[node];

    // self-loop first (src == dst == node)
    float d = hi.x * hi.x + hi.y * hi.y;
    float logit = waveAllReduceAdd(d);
    float sig = 1.0f / (1.0f + __expf(-logit));
    float alpha = (aln + arn) * sig;

    float m = alpha;
    float denom = 1.0f;           // exp(alpha - m) = 1
    float accx = hi.x, accy = hi.y;

    int start = row_ptr[node];
    int deg = counts[node];
    int sNext = (deg > 0) ? csr[start] : 0;
    for (int i = 0; i < deg; i++) {
        int s = sNext;
        if (i + 1 < deg) sNext = csr[start + i + 1];
        float2 hj = *(const float2*)&H[(size_t)s * C + 2 * lane];
        float als = al[s];
        float dd = hi.x * hj.x + hi.y * hj.y;
        float lg = waveAllReduceAdd(dd);
        float sg = 1.0f / (1.0f + __expf(-lg));
        float a2 = (als + arn) * sg;
        float mn = fmaxf(m, a2);
        float sc = __expf(m - mn);
        float p = __expf(a2 - mn);
        denom = denom * sc + p;
        accx = accx * sc + p * hj.x;
        accy = accy * sc + p * hj.y;
        m = mn;
    }

    float2 bv = *(const float2*)&bvec[2 * lane];
    float inv = 1.0f / (denom + EPSV);
    float ox = accx * inv + bv.x;
    float oy = accy * inv + bv.y;
    if (doRelu) { ox = fmaxf(ox, 0.0f); oy = fmaxf(oy, 0.0f); }
    *(float2*)&O[(size_t)node * C + 2 * lane] = make_float2(ox, oy);
}

// ---------------- edge classifier: out[e] = [h[row];h[col]] @ Wc + bc ------

__global__ __launch_bounds__(256) void classifier_kernel(const float* __restrict__ H2, const int* __restrict__ rowA,
                                                         const int* __restrict__ colA, const float* __restrict__ Wc,
                                                         const float* __restrict__ bc, float* __restrict__ out, int e) {
    int lane = threadIdx.x & 63;
    int wave = (blockIdx.x * 256 + threadIdx.x) >> 6;
    int numWaves = (gridDim.x * 256) >> 6;

    // per-lane weights: dims 2*lane, 2*lane+1, 128+2*lane, 129+2*lane
    float4 w0 = *(const float4*)&Wc[(2 * lane) * 4];
    float4 w1 = *(const float4*)&Wc[(2 * lane + 1) * 4];
    float4 w2 = *(const float4*)&Wc[(C + 2 * lane) * 4];
    float4 w3 = *(const float4*)&Wc[(C + 2 * lane + 1) * 4];
    float4 bcv = *(const float4*)bc;

    for (int ei = wave; ei < e; ei += numWaves) {
        int r = rowA[ei];
        int c = colA[ei];
        float2 hr = *(const float2*)&H2[(size_t)r * C + 2 * lane];
        float2 hc = *(const float2*)&H2[(size_t)c * C + 2 * lane];
        float p0 = hr.x * w0.x + hr.y * w1.x + hc.x * w2.x + hc.y * w3.x;
        float p1 = hr.x * w0.y + hr.y * w1.y + hc.x * w2.y + hc.y * w3.y;
        float p2 = hr.x * w0.z + hr.y * w1.z + hc.x * w2.z + hc.y * w3.z;
        float p3 = hr.x * w0.w + hr.y * w1.w + hc.x * w2.w + hc.y * w3.w;
        p0 = waveAllReduceAdd(p0);
        p1 = waveAllReduceAdd(p1);
        p2 = waveAllReduceAdd(p2);
        p3 = waveAllReduceAdd(p3);
        if (lane == 0) {
            float4 o = make_float4(p0 + bcv.x, p1 + bcv.y, p2 + bcv.z, p3 + bcv.w);
            *(float4*)&out[(size_t)ei * 4] = o;
        }
    }
}

// ---------------- host ----------------

extern "C" void kernel_launch(void* const* d_in, const int* in_sizes, int n_in,
                              void* d_out, int out_size, void* d_ws, size_t ws_size,
                              hipStream_t stream) {
    const float* x     = (const float*)d_in[0];
    const int*   ei    = (const int*)d_in[1];
    const float* W1    = (const float*)d_in[2];
    const float* attl1 = (const float*)d_in[3];
    const float* attr1 = (const float*)d_in[4];
    const float* b1    = (const float*)d_in[5];
    const float* W2    = (const float*)d_in[6];
    const float* attl2 = (const float*)d_in[7];
    const float* attr2 = (const float*)d_in[8];
    const float* b2    = (const float*)d_in[9];
    const float* Wc    = (const float*)d_in[10];
    const float* bc    = (const float*)d_in[11];
    float* out = (float*)d_out;

    const int N = in_sizes[0] / C;      // 50000
    const int E = in_sizes[1] / 2;      // 800000
    const int* rowA = ei;
    const int* colA = ei + E;

    // workspace layout
    float* bufA   = (float*)d_ws;                    // N*C
    float* bufB   = bufA + (size_t)N * C;            // N*C
    float* al     = bufB + (size_t)N * C;            // N
    float* ar     = al + N;                          // N
    int*   counts = (int*)(ar + N);                  // N
    int*   row_ptr= counts + N;                      // N
    int*   cursor = row_ptr + N;                     // N
    int*   bsums  = cursor + N;                      // 256
    int*   csr    = bsums + 256;                     // E

    const int nbN = (N + 255) / 256;
    const int nbE = (E + 255) / 256;

    zero_kernel<<<nbN, 256, 0, stream>>>(counts, N);
    hist_kernel<<<nbE, 256, 0, stream>>>(colA, counts, E);
    scanA_kernel<<<nbN, 256, 0, stream>>>(counts, row_ptr, bsums, N);
    scanB_kernel<<<1, 256, 0, stream>>>(bsums, nbN);
    scanC_kernel<<<nbN, 256, 0, stream>>>(row_ptr, bsums, cursor, N);
    scatter_kernel<<<nbE, 256, 0, stream>>>(rowA, colA, cursor, csr, E);

    const int nRowGroups = N / 4;   // N divisible by 4
    const int gemmBlocks = (nRowGroups * 32 + 255) / 256;
    const int nodeBlocks = (N + 3) / 4;

    // layer 1
    gemm_kernel<<<gemmBlocks, 256, 0, stream>>>(x, W1, bufA, nRowGroups);
    att_kernel<<<nodeBlocks, 256, 0, stream>>>(bufA, attl1, attr1, al, ar, N);
    agg_kernel<<<nodeBlocks, 256, 0, stream>>>(bufA, csr, row_ptr, counts, al, ar, b1, bufB, N, 1);

    // layer 2
    gemm_kernel<<<gemmBlocks, 256, 0, stream>>>(bufB, W2, bufA, nRowGroups);
    att_kernel<<<nodeBlocks, 256, 0, stream>>>(bufA, attl2, attr2, al, ar, N);
    agg_kernel<<<nodeBlocks, 256, 0, stream>>>(bufA, csr, row_ptr, counts, al, ar, b2, bufB, N, 0);

    // classifier
    classifier_kernel<<<2048, 256, 0, stream>>>(bufB, rowA, colA, Wc, bc, out, E);
}

// Round 2
// 481.657 us; speedup vs baseline: 1.5007x; 1.5007x over previous
//
#include <hip/hip_runtime.h>
#include <math.h>

#define C 128
#define EPSV 1e-16f

__device__ __forceinline__ float waveAllReduceAdd(float v) {
    #pragma unroll
    for (int off = 32; off >= 1; off >>= 1) v += __shfl_xor(v, off);
    return v;
}

// ---------------- sort-by-dst (CSR build) ----------------

__global__ __launch_bounds__(256) void zero_kernel(int* __restrict__ p, int n) {
    int i = blockIdx.x * 256 + threadIdx.x;
    if (i < n) p[i] = 0;
}

__global__ __launch_bounds__(256) void hist_kernel(const int* __restrict__ col, int* __restrict__ counts, int e) {
    int i = blockIdx.x * 256 + threadIdx.x;
    if (i < e) atomicAdd(&counts[col[i]], 1);
}

__global__ __launch_bounds__(256) void scanA_kernel(const int* __restrict__ counts, int* __restrict__ row_ptr,
                                                    int* __restrict__ bsums, int n) {
    __shared__ int sh[256];
    int tid = threadIdx.x;
    int i = blockIdx.x * 256 + tid;
    int v = (i < n) ? counts[i] : 0;
    sh[tid] = v;
    __syncthreads();
    #pragma unroll
    for (int off = 1; off < 256; off <<= 1) {
        int t = (tid >= off) ? sh[tid - off] : 0;
        __syncthreads();
        sh[tid] += t;
        __syncthreads();
    }
    if (i < n) row_ptr[i] = sh[tid] - v;            // chunk-local exclusive
    if (tid == 255) bsums[blockIdx.x] = sh[255];    // chunk total
}

__global__ __launch_bounds__(256) void scanB_kernel(int* __restrict__ bsums, int nb) {
    __shared__ int sh[256];
    int tid = threadIdx.x;
    int v = (tid < nb) ? bsums[tid] : 0;
    sh[tid] = v;
    __syncthreads();
    #pragma unroll
    for (int off = 1; off < 256; off <<= 1) {
        int t = (tid >= off) ? sh[tid - off] : 0;
        __syncthreads();
        sh[tid] += t;
        __syncthreads();
    }
    bsums[tid] = sh[tid] - v;                       // exclusive over block sums
}

__global__ __launch_bounds__(256) void scanC_kernel(int* __restrict__ row_ptr, const int* __restrict__ bsums,
                                                    int* __restrict__ cursor, int n) {
    int i = blockIdx.x * 256 + threadIdx.x;
    if (i < n) {
        int rp = row_ptr[i] + bsums[blockIdx.x];
        row_ptr[i] = rp;
        cursor[i] = rp;
    }
}

__global__ __launch_bounds__(256) void scatter_kernel(const int* __restrict__ rowA, const int* __restrict__ colA,
                                                      int* __restrict__ cursor, int* __restrict__ csr, int e) {
    int i = blockIdx.x * 256 + threadIdx.x;
    if (i < e) {
        int c = colA[i];
        int p = atomicAdd(&cursor[c], 1);
        csr[p] = rowA[i];
    }
}

// ---------------- GEMM: O[n][128] = A[n][128] @ W[128][128] ----------------
// thread = 4 rows x 4 cols, float4 A-loads

__global__ __launch_bounds__(256) void gemm_kernel(const float* __restrict__ A, const float* __restrict__ W,
                                                   float* __restrict__ O, int nRowGroups) {
    int t = blockIdx.x * 256 + threadIdx.x;
    int rg = t >> 5;
    if (rg >= nRowGroups) return;
    int cg = t & 31;
    const float4* W4 = (const float4*)W;
    const float4* A4 = (const float4*)(A + (size_t)rg * 4 * C);
    float4 acc0 = {0,0,0,0}, acc1 = {0,0,0,0}, acc2 = {0,0,0,0}, acc3 = {0,0,0,0};
    #pragma unroll 4
    for (int k4 = 0; k4 < 32; k4++) {
        float4 a0 = A4[k4];
        float4 a1 = A4[32 + k4];
        float4 a2 = A4[64 + k4];
        float4 a3 = A4[96 + k4];
        #pragma unroll
        for (int j = 0; j < 4; j++) {
            float4 w = W4[(k4 * 4 + j) * 32 + cg];
            float av0 = j == 0 ? a0.x : j == 1 ? a0.y : j == 2 ? a0.z : a0.w;
            float av1 = j == 0 ? a1.x : j == 1 ? a1.y : j == 2 ? a1.z : a1.w;
            float av2 = j == 0 ? a2.x : j == 1 ? a2.y : j == 2 ? a2.z : a2.w;
            float av3 = j == 0 ? a3.x : j == 1 ? a3.y : j == 2 ? a3.z : a3.w;
            acc0.x += av0 * w.x; acc0.y += av0 * w.y; acc0.z += av0 * w.z; acc0.w += av0 * w.w;
            acc1.x += av1 * w.x; acc1.y += av1 * w.y; acc1.z += av1 * w.z; acc1.w += av1 * w.w;
            acc2.x += av2 * w.x; acc2.y += av2 * w.y; acc2.z += av2 * w.z; acc2.w += av2 * w.w;
            acc3.x += av3 * w.x; acc3.y += av3 * w.y; acc3.z += av3 * w.z; acc3.w += av3 * w.w;
        }
    }
    float4* O4 = (float4*)(O + (size_t)rg * 4 * C);
    O4[cg] = acc0;
    O4[32 + cg] = acc1;
    O4[64 + cg] = acc2;
    O4[96 + cg] = acc3;
}

// ---------------- per-node attention dot precompute ----------------

__global__ __launch_bounds__(256) void att_kernel(const float* __restrict__ H, const float* __restrict__ attl,
                                                  const float* __restrict__ attr, float* __restrict__ al,
                                                  float* __restrict__ ar, int n) {
    int node = blockIdx.x * 4 + (threadIdx.x >> 6);
    int lane = threadIdx.x & 63;
    if (node >= n) return;
    float2 h2 = *(const float2*)&H[(size_t)node * C + 2 * lane];
    float2 l2 = *(const float2*)&attl[2 * lane];
    float2 r2 = *(const float2*)&attr[2 * lane];
    float sl = h2.x * l2.x + h2.y * l2.y;
    float sr = h2.x * r2.x + h2.y * r2.y;
    #pragma unroll
    for (int off = 32; off >= 1; off >>= 1) {
        sl += __shfl_xor(sl, off);
        sr += __shfl_xor(sr, off);
    }
    if (lane == 0) { al[node] = sl; ar[node] = sr; }
}

// ---------------- per-node aggregation (online softmax, wave per node) -----
// batched 4 edges/iter for ILP

__global__ __launch_bounds__(256) void agg_kernel(const float* __restrict__ H, const int* __restrict__ csr,
                                                  const int* __restrict__ row_ptr, const int* __restrict__ counts,
                                                  const float* __restrict__ al, const float* __restrict__ ar,
                                                  const float* __restrict__ bvec, float* __restrict__ O,
                                                  int n, int doRelu) {
    int node = blockIdx.x * 4 + (threadIdx.x >> 6);
    int lane = threadIdx.x & 63;
    if (node >= n) return;

    float2 hi = *(const float2*)&H[(size_t)node * C + 2 * lane];
    float aln = al[node];
    float arn = ar[node];

    // self-loop first (src == dst == node)
    float d = hi.x * hi.x + hi.y * hi.y;
    float logit = waveAllReduceAdd(d);
    float sig = 1.0f / (1.0f + __expf(-logit));
    float alpha = (aln + arn) * sig;

    float m = alpha;
    float denom = 1.0f;           // exp(alpha - m) = 1
    float accx = hi.x, accy = hi.y;

    int start = row_ptr[node];
    int deg = counts[node];

    int i = 0;
    for (; i + 4 <= deg; i += 4) {
        int s0 = csr[start + i];
        int s1 = csr[start + i + 1];
        int s2 = csr[start + i + 2];
        int s3 = csr[start + i + 3];
        float2 h0 = *(const float2*)&H[(size_t)s0 * C + 2 * lane];
        float2 h1 = *(const float2*)&H[(size_t)s1 * C + 2 * lane];
        float2 h2v = *(const float2*)&H[(size_t)s2 * C + 2 * lane];
        float2 h3 = *(const float2*)&H[(size_t)s3 * C + 2 * lane];
        float a0 = al[s0];
        float a1 = al[s1];
        float a2 = al[s2];
        float a3 = al[s3];
        float d0 = hi.x * h0.x + hi.y * h0.y;
        float d1 = hi.x * h1.x + hi.y * h1.y;
        float d2 = hi.x * h2v.x + hi.y * h2v.y;
        float d3 = hi.x * h3.x + hi.y * h3.y;
        #pragma unroll
        for (int off = 32; off >= 1; off >>= 1) {
            d0 += __shfl_xor(d0, off);
            d1 += __shfl_xor(d1, off);
            d2 += __shfl_xor(d2, off);
            d3 += __shfl_xor(d3, off);
        }
        float g0 = (a0 + arn) / (1.0f + __expf(-d0));
        float g1 = (a1 + arn) / (1.0f + __expf(-d1));
        float g2 = (a2 + arn) / (1.0f + __expf(-d2));
        float g3 = (a3 + arn) / (1.0f + __expf(-d3));
        float mb = fmaxf(fmaxf(g0, g1), fmaxf(g2, g3));
        float mn = fmaxf(m, mb);
        float sc = __expf(m - mn);
        float p0 = __expf(g0 - mn);
        float p1 = __expf(g1 - mn);
        float p2 = __expf(g2 - mn);
        float p3 = __expf(g3 - mn);
        denom = denom * sc + p0 + p1 + p2 + p3;
        accx = accx * sc + p0 * h0.x + p1 * h1.x + p2 * h2v.x + p3 * h3.x;
        accy = accy * sc + p0 * h0.y + p1 * h1.y + p2 * h2v.y + p3 * h3.y;
        m = mn;
    }
    for (; i < deg; i++) {
        int s = csr[start + i];
        float2 hj = *(const float2*)&H[(size_t)s * C + 2 * lane];
        float als = al[s];
        float dd = hi.x * hj.x + hi.y * hj.y;
        float lg = waveAllReduceAdd(dd);
        float sg = 1.0f / (1.0f + __expf(-lg));
        float a2 = (als + arn) * sg;
        float mn = fmaxf(m, a2);
        float sc = __expf(m - mn);
        float p = __expf(a2 - mn);
        denom = denom * sc + p;
        accx = accx * sc + p * hj.x;
        accy = accy * sc + p * hj.y;
        m = mn;
    }

    float2 bv = *(const float2*)&bvec[2 * lane];
    float inv = 1.0f / (denom + EPSV);
    float ox = accx * inv + bv.x;
    float oy = accy * inv + bv.y;
    if (doRelu) { ox = fmaxf(ox, 0.0f); oy = fmaxf(oy, 0.0f); }
    *(float2*)&O[(size_t)node * C + 2 * lane] = make_float2(ox, oy);
}

// ---------------- classifier: per-node projection then per-edge add -------
// out[e] = h[row] @ Wc_top + h[col] @ Wc_bot + bc

__global__ __launch_bounds__(256) void proj_kernel(const float* __restrict__ H2, const float* __restrict__ Wc,
                                                   float* __restrict__ P1, float* __restrict__ P2, int n) {
    int node = blockIdx.x * 4 + (threadIdx.x >> 6);
    int lane = threadIdx.x & 63;
    if (node >= n) return;
    float2 h2 = *(const float2*)&H2[(size_t)node * C + 2 * lane];
    float4 w0 = *(const float4*)&Wc[(2 * lane) * 4];
    float4 w1 = *(const float4*)&Wc[(2 * lane + 1) * 4];
    float4 w2 = *(const float4*)&Wc[(C + 2 * lane) * 4];
    float4 w3 = *(const float4*)&Wc[(C + 2 * lane + 1) * 4];
    float p0 = h2.x * w0.x + h2.y * w1.x;
    float p1 = h2.x * w0.y + h2.y * w1.y;
    float p2 = h2.x * w0.z + h2.y * w1.z;
    float p3 = h2.x * w0.w + h2.y * w1.w;
    float q0 = h2.x * w2.x + h2.y * w3.x;
    float q1 = h2.x * w2.y + h2.y * w3.y;
    float q2 = h2.x * w2.z + h2.y * w3.z;
    float q3 = h2.x * w2.w + h2.y * w3.w;
    #pragma unroll
    for (int off = 32; off >= 1; off >>= 1) {
        p0 += __shfl_xor(p0, off);
        p1 += __shfl_xor(p1, off);
        p2 += __shfl_xor(p2, off);
        p3 += __shfl_xor(p3, off);
        q0 += __shfl_xor(q0, off);
        q1 += __shfl_xor(q1, off);
        q2 += __shfl_xor(q2, off);
        q3 += __shfl_xor(q3, off);
    }
    if (lane == 0) {
        *(float4*)&P1[(size_t)node * 4] = make_float4(p0, p1, p2, p3);
        *(float4*)&P2[(size_t)node * 4] = make_float4(q0, q1, q2, q3);
    }
}

__global__ __launch_bounds__(256) void edge_out_kernel(const float4* __restrict__ P1, const float4* __restrict__ P2,
                                                       const int* __restrict__ rowA, const int* __restrict__ colA,
                                                       const float* __restrict__ bc, float4* __restrict__ out, int e) {
    int i = blockIdx.x * 256 + threadIdx.x;
    if (i >= e) return;
    float4 a = P1[rowA[i]];
    float4 b = P2[colA[i]];
    float4 bcv = *(const float4*)bc;
    out[i] = make_float4(a.x + b.x + bcv.x, a.y + b.y + bcv.y, a.z + b.z + bcv.z, a.w + b.w + bcv.w);
}

// ---------------- host ----------------

extern "C" void kernel_launch(void* const* d_in, const int* in_sizes, int n_in,
                              void* d_out, int out_size, void* d_ws, size_t ws_size,
                              hipStream_t stream) {
    const float* x     = (const float*)d_in[0];
    const int*   ei    = (const int*)d_in[1];
    const float* W1    = (const float*)d_in[2];
    const float* attl1 = (const float*)d_in[3];
    const float* attr1 = (const float*)d_in[4];
    const float* b1    = (const float*)d_in[5];
    const float* W2    = (const float*)d_in[6];
    const float* attl2 = (const float*)d_in[7];
    const float* attr2 = (const float*)d_in[8];
    const float* b2    = (const float*)d_in[9];
    const float* Wc    = (const float*)d_in[10];
    const float* bc    = (const float*)d_in[11];
    float* out = (float*)d_out;

    const int N = in_sizes[0] / C;      // 50000
    const int E = in_sizes[1] / 2;      // 800000
    const int* rowA = ei;
    const int* colA = ei + E;

    // workspace layout
    float* bufA   = (float*)d_ws;                    // N*C
    float* bufB   = bufA + (size_t)N * C;            // N*C
    float* al     = bufB + (size_t)N * C;            // N
    float* ar     = al + N;                          // N
    int*   counts = (int*)(ar + N);                  // N
    int*   row_ptr= counts + N;                      // N
    int*   cursor = row_ptr + N;                     // N
    int*   bsums  = cursor + N;                      // 256
    int*   csr    = bsums + 256;                     // E
    // P1/P2 reuse bufA (free after layer-2 agg writes bufB)
    float* P1 = bufA;                                // N*4
    float* P2 = bufA + (size_t)N * 4;                // N*4

    const int nbN = (N + 255) / 256;
    const int nbE = (E + 255) / 256;

    zero_kernel<<<nbN, 256, 0, stream>>>(counts, N);
    hist_kernel<<<nbE, 256, 0, stream>>>(colA, counts, E);
    scanA_kernel<<<nbN, 256, 0, stream>>>(counts, row_ptr, bsums, N);
    scanB_kernel<<<1, 256, 0, stream>>>(bsums, nbN);
    scanC_kernel<<<nbN, 256, 0, stream>>>(row_ptr, bsums, cursor, N);
    scatter_kernel<<<nbE, 256, 0, stream>>>(rowA, colA, cursor, csr, E);

    const int nRowGroups = N / 4;
    const int gemmBlocks = (nRowGroups * 32 + 255) / 256;
    const int nodeBlocks = (N + 3) / 4;

    // layer 1
    gemm_kernel<<<gemmBlocks, 256, 0, stream>>>(x, W1, bufA, nRowGroups);
    att_kernel<<<nodeBlocks, 256, 0, stream>>>(bufA, attl1, attr1, al, ar, N);
    agg_kernel<<<nodeBlocks, 256, 0, stream>>>(bufA, csr, row_ptr, counts, al, ar, b1, bufB, N, 1);

    // layer 2
    gemm_kernel<<<gemmBlocks, 256, 0, stream>>>(bufB, W2, bufA, nRowGroups);
    att_kernel<<<nodeBlocks, 256, 0, stream>>>(bufA, attl2, attr2, al, ar, N);
    agg_kernel<<<nodeBlocks, 256, 0, stream>>>(bufA, csr, row_ptr, counts, al, ar, b2, bufB, N, 0);

    // classifier: project nodes, then cheap per-edge combine
    proj_kernel<<<nodeBlocks, 256, 0, stream>>>(bufB, Wc, P1, P2, N);
    edge_out_kernel<<<nbE, 256, 0, stream>>>((const float4*)P1, (const float4*)P2, rowA, colA, bc, (float4*)out, E);
}